// Round 1
// 149.687 us; speedup vs baseline: 1.0101x; 1.0101x over previous
//
#include <hip/hip_runtime.h>

#define NN   4096
#define FIN  512
#define FOUT 256
#define ALPHA 0.2f

typedef __attribute__((ext_vector_type(8))) short short8;
typedef __attribute__((ext_vector_type(4))) float f32x4;
typedef unsigned short u16;

__device__ __forceinline__ u16 f2bf(float x) {   // round-to-nearest-even
    union { float f; unsigned u; } v; v.f = x;
    unsigned r = v.u + 0x7FFF + ((v.u >> 16) & 1);
    return (u16)(r >> 16);
}

// ---------------- Kernel 0: Wt[f][k] bf16 = transpose(W [k][f] fp32) ----------------
// Also zeroes fs/fd for k_proj's atomic accumulation (32 blk x 256 thr = 8192 = 2*NN).
__global__ __launch_bounds__(256) void k_wt(const float* __restrict__ W,
                                            u16* __restrict__ Wt,
                                            float* __restrict__ fs,
                                            float* __restrict__ fd) {
    __shared__ float s[64 * 65];
    const int t  = threadIdx.x;
    const int g  = (blockIdx.y * gridDim.x + blockIdx.x) * 256 + t;
    if (g < NN) fs[g] = 0.f; else fd[g - NN] = 0.f;
    const int f0 = blockIdx.x * 64;
    const int k0 = blockIdx.y * 64;
    #pragma unroll
    for (int p = 0; p < 4; ++p) {
        int q = t + 256 * p, rr = q >> 4, cc = q & 15;
        float4 w4 = *(const float4*)&W[(size_t)(k0 + rr) * FOUT + f0 + cc * 4];
        s[(cc * 4 + 0) * 65 + rr] = w4.x;
        s[(cc * 4 + 1) * 65 + rr] = w4.y;
        s[(cc * 4 + 2) * 65 + rr] = w4.z;
        s[(cc * 4 + 3) * 65 + rr] = w4.w;
    }
    __syncthreads();
    #pragma unroll
    for (int p = 0; p < 4; ++p) {
        int q = t + 256 * p, f = q >> 4, kg = q & 15;
        ushort4 o;
        o.x = f2bf(s[f * 65 + kg * 4 + 0]);
        o.y = f2bf(s[f * 65 + kg * 4 + 1]);
        o.z = f2bf(s[f * 65 + kg * 4 + 2]);
        o.w = f2bf(s[f * 65 + kg * 4 + 3]);
        *(ushort4*)&Wt[(size_t)(f0 + f) * FIN + k0 + kg * 4] = o;
    }
}

// ------- Kernel 1: proj -> whT bf16 tiles + f_src/f_dst partials (wh fp32 eliminated) -------
// Block: 32 i x 64 f. Stage full 32x512 h slab once; stream Wt B-frags from L2.
// whT layout: [j/32][f][j&31] bf16, tile = FOUT*32 = 8192 elems.
#define HS 520   // u16 LDS row stride (1040 B = 65*16, aligned)
__global__ __launch_bounds__(256) void k_proj(const float* __restrict__ h,
                                              const u16* __restrict__ Wt,
                                              const float* __restrict__ bias,
                                              const float* __restrict__ a1,
                                              const float* __restrict__ a2,
                                              u16* __restrict__ whT,
                                              float* __restrict__ fs,
                                              float* __restrict__ fd) {
    __shared__ u16 s_h[32 * HS];   // 32 rows x 512 k bf16
    const int t  = threadIdx.x;
    const int f0 = blockIdx.x * 64;
    const int i0 = blockIdx.y * 32;
    // stage h slab: 4096 float4 over 256 threads
    #pragma unroll
    for (int p = 0; p < 16; ++p) {
        int q = t + 256 * p, row = q >> 7, c4 = q & 127;
        float4 v = *(const float4*)&h[(size_t)(i0 + row) * FIN + c4 * 4];
        ushort4 o; o.x = f2bf(v.x); o.y = f2bf(v.y); o.z = f2bf(v.z); o.w = f2bf(v.w);
        *(ushort4*)&s_h[row * HS + c4 * 4] = o;
    }
    __syncthreads();
    const int w = t >> 6, l = t & 63, n = l & 15, quad = l >> 4;
    const int hh = w & 1, fh = w >> 1;
    f32x4 acc[2] = {{0.f,0.f,0.f,0.f},{0.f,0.f,0.f,0.f}};
    #pragma unroll
    for (int k0 = 0; k0 < FIN; k0 += 32) {
        short8 a = *(const short8*)&s_h[(hh * 16 + n) * HS + k0 + quad * 8];
        short8 b0 = *(const short8*)&Wt[(size_t)(f0 + fh * 32 + n) * FIN + k0 + quad * 8];
        short8 b1 = *(const short8*)&Wt[(size_t)(f0 + fh * 32 + 16 + n) * FIN + k0 + quad * 8];
        acc[0] = __builtin_amdgcn_mfma_f32_16x16x32_bf16(a, b0, acc[0], 0, 0, 0);
        acc[1] = __builtin_amdgcn_mfma_f32_16x16x32_bf16(a, b1, acc[1], 0, 0, 0);
    }
    const int fb = f0 + fh * 32 + n;
    const float bv0 = bias[fb],  bv1 = bias[fb + 16];
    const float a10 = a1[fb],    a11 = a1[fb + 16];
    const float a20 = a2[fb],    a21 = a2[fb + 16];
    u16* wt_tile = whT + (size_t)(i0 >> 5) * (FOUT * 32);
    float d1[4], d2[4];
    #pragma unroll
    for (int r = 0; r < 4; ++r) {
        const int ic = hh * 16 + quad * 4 + r;       // i - i0
        const float v0 = acc[0][r] + bv0;
        const float v1 = acc[1][r] + bv1;
        wt_tile[fb * 32 + ic]        = f2bf(v0);
        wt_tile[(fb + 16) * 32 + ic] = f2bf(v1);
        d1[r] = v0 * a10 + v1 * a11;
        d2[r] = v0 * a20 + v1 * a21;
    }
    // reduce over the 16 n-lanes (l = quad*16 + n, xor 1..8 stays in group)
    #pragma unroll
    for (int m = 1; m < 16; m <<= 1) {
        #pragma unroll
        for (int r = 0; r < 4; ++r) {
            d1[r] += __shfl_xor(d1[r], m);
            d2[r] += __shfl_xor(d2[r], m);
        }
    }
    if (n == 0) {
        #pragma unroll
        for (int r = 0; r < 4; ++r) {
            const int i = i0 + hh * 16 + quad * 4 + r;
            atomicAdd(&fs[i], d1[r]);
            atomicAdd(&fd[i], d2[r]);
        }
    }
}

// ------ Kernel 2: fused mask+exp + MFMA P@wh; dbuf P tile, 1 barrier/iter ------
// BI=32 i-rows/block, TJ=64 j/iter, C j-chunks. XOR-swizzled P tile (row 128B):
// byte ^= (row&7)<<4 -> conflict-free ds_write_b64 / ds_read_b128.
#define BI 32
#define TJ 64
__global__ __launch_bounds__(256) void k_attn(const int* __restrict__ adj,
                                              const u16* __restrict__ whT,
                                              const float* __restrict__ fs,
                                              const float* __restrict__ fd,
                                              const float* __restrict__ ab,
                                              float* __restrict__ part,
                                              float* __restrict__ psum) {
    __shared__ u16 s_p[2][BI * 64];    // 2 x 4 KiB, row stride 128 B, swizzled
    const int t  = threadIdx.x;
    const int i0 = blockIdx.x * BI;
    const int c  = blockIdx.y;
    const int jchunk = NN / gridDim.y;
    const int jbeg = c * jchunk, jend = jbeg + jchunk;
    // phase-A ids: 8 p-values/thread: rows rh, rh+16; j = jq*4..+4
    const int jq = t & 15, rh = t >> 4;
    const float fs0 = fs[i0 + rh] + ab[0];
    const float fs1 = fs[i0 + rh + 16] + ab[0];
    // MFMA ids
    const int w = t >> 6, l = t & 63, n = l & 15, quad = l >> 4;

    f32x4 acc[2][4] = {{{0.f,0.f,0.f,0.f},{0.f,0.f,0.f,0.f},{0.f,0.f,0.f,0.f},{0.f,0.f,0.f,0.f}},
                       {{0.f,0.f,0.f,0.f},{0.f,0.f,0.f,0.f},{0.f,0.f,0.f,0.f},{0.f,0.f,0.f,0.f}}};
    float rs0 = 0.f, rs1 = 0.f;

    // prefetch iter-0 adj/fd
    int4   av0 = *(const int4*)&adj[(size_t)(i0 + rh) * NN + jbeg + jq * 4];
    int4   av1 = *(const int4*)&adj[(size_t)(i0 + rh + 16) * NN + jbeg + jq * 4];
    float4 fdv = *(const float4*)&fd[jbeg + jq * 4];

    const int wbase = rh * 128 + ((jq * 8) ^ ((rh & 7) << 4));   // write swizzle
    const int rsw   = (n & 7) << 4;                              // read swizzle mask
    int pb = 0;
    for (int j0 = jbeg; j0 < jend; j0 += TJ) {
        // ---- B-frags issued first: L2 latency hides under p-compute ----
        short8 b[2][4];   // [s][u]
        #pragma unroll
        for (int s = 0; s < 2; ++s) {
            const u16* tb = whT + (size_t)((j0 >> 5) + s) * (FOUT * 32) + quad * 8;
            #pragma unroll
            for (int u = 0; u < 4; ++u)
                b[s][u] = *(const short8*)&tb[(w * 64 + u * 16 + n) * 32];
        }
        // ---- compute p from prefetched regs ----
        ushort4 o0, o1;
        {
            float x, p;
            x = fs0 + fdv.x; x = x > 0.f ? x : ALPHA * x; p = av0.x > 0 ? __expf(x) : 0.f; o0.x = f2bf(p); rs0 += p;
            x = fs0 + fdv.y; x = x > 0.f ? x : ALPHA * x; p = av0.y > 0 ? __expf(x) : 0.f; o0.y = f2bf(p); rs0 += p;
            x = fs0 + fdv.z; x = x > 0.f ? x : ALPHA * x; p = av0.z > 0 ? __expf(x) : 0.f; o0.z = f2bf(p); rs0 += p;
            x = fs0 + fdv.w; x = x > 0.f ? x : ALPHA * x; p = av0.w > 0 ? __expf(x) : 0.f; o0.w = f2bf(p); rs0 += p;
            x = fs1 + fdv.x; x = x > 0.f ? x : ALPHA * x; p = av1.x > 0 ? __expf(x) : 0.f; o1.x = f2bf(p); rs1 += p;
            x = fs1 + fdv.y; x = x > 0.f ? x : ALPHA * x; p = av1.y > 0 ? __expf(x) : 0.f; o1.y = f2bf(p); rs1 += p;
            x = fs1 + fdv.z; x = x > 0.f ? x : ALPHA * x; p = av1.z > 0 ? __expf(x) : 0.f; o1.z = f2bf(p); rs1 += p;
            x = fs1 + fdv.w; x = x > 0.f ? x : ALPHA * x; p = av1.w > 0 ? __expf(x) : 0.f; o1.w = f2bf(p); rs1 += p;
        }
        // ---- write this iter's P tile into buffer pb (no barrier needed before:
        //      all reads of pb finished before barrier(i-1), writes here are after it) ----
        char* spB = (char*)s_p + pb * 4096;
        *(ushort4*)(spB + wbase)        = o0;   // row rh
        *(ushort4*)(spB + 2048 + wbase) = o1;   // row rh+16 (same xor: (rh+16)&7 == rh&7)
        // ---- prefetch next iter's adj/fd (off critical path) ----
        if (j0 + TJ < jend) {
            av0 = *(const int4*)&adj[(size_t)(i0 + rh) * NN + j0 + TJ + jq * 4];
            av1 = *(const int4*)&adj[(size_t)(i0 + rh + 16) * NN + j0 + TJ + jq * 4];
            fdv = *(const float4*)&fd[j0 + TJ + jq * 4];
        }
        __syncthreads();   // P tile pb visible
        // ---- MFMA: 32i x 64f slice per wave ----
        __builtin_amdgcn_s_setprio(1);
        #pragma unroll
        for (int s = 0; s < 2; ++s) {
            const int rb = n * 128 + ((s * 64 + quad * 16) ^ rsw);
            short8 a0  = *(const short8*)(spB + rb);          // row n
            short8 a1f = *(const short8*)(spB + 2048 + rb);   // row 16+n
            #pragma unroll
            for (int u = 0; u < 4; ++u) {
                acc[0][u] = __builtin_amdgcn_mfma_f32_16x16x32_bf16(a0,  b[s][u], acc[0][u], 0, 0, 0);
                acc[1][u] = __builtin_amdgcn_mfma_f32_16x16x32_bf16(a1f, b[s][u], acc[1][u], 0, 0, 0);
            }
        }
        __builtin_amdgcn_s_setprio(0);
        pb ^= 1;
    }
    // ---- partial denominators: reduce over the 16 jq lanes ----
    #pragma unroll
    for (int m = 8; m > 0; m >>= 1) {
        rs0 += __shfl_xor(rs0, m);
        rs1 += __shfl_xor(rs1, m);
    }
    if (jq == 0) {
        psum[(size_t)c * NN + i0 + rh]      = rs0;
        psum[(size_t)c * NN + i0 + rh + 16] = rs1;
    }
    // ---- partial numerators ----
    float* pc = part + ((size_t)c * NN + i0) * FOUT;
    #pragma unroll
    for (int hf = 0; hf < 2; ++hf)
        #pragma unroll
        for (int u = 0; u < 4; ++u)
            #pragma unroll
            for (int r = 0; r < 4; ++r)
                pc[(size_t)(hf * 16 + quad * 4 + r) * FOUT + w * 64 + u * 16 + n] = acc[hf][u][r];
}

// ------ Kernel 3: combine partials, normalize, elu ------
__global__ __launch_bounds__(256) void k_fin(const float* __restrict__ part,
                                             const float* __restrict__ psum,
                                             float* __restrict__ out, int C) {
    const int g = blockIdx.x * 256 + threadIdx.x;
    const int i = g >> 6;
    const size_t s4 = (size_t)NN * FOUT / 4;
    float4 a = ((const float4*)part)[g];
    float s = psum[i];
    for (int c = 1; c < C; ++c) {
        float4 bb = ((const float4*)part)[g + (size_t)c * s4];
        a.x += bb.x; a.y += bb.y; a.z += bb.z; a.w += bb.w;
        s += psum[(size_t)c * NN + i];
    }
    const float inv = 1.0f / s;
    a.x *= inv; a.y *= inv; a.z *= inv; a.w *= inv;
    a.x = a.x > 0.f ? a.x : __expf(a.x) - 1.f;
    a.y = a.y > 0.f ? a.y : __expf(a.y) - 1.f;
    a.z = a.z > 0.f ? a.z : __expf(a.z) - 1.f;
    a.w = a.w > 0.f ? a.w : __expf(a.w) - 1.f;
    ((float4*)out)[g] = a;
}

extern "C" void kernel_launch(void* const* d_in, const int* in_sizes, int n_in,
                              void* d_out, int out_size, void* d_ws, size_t ws_size,
                              hipStream_t stream) {
    const int*   adj = (const int*)  d_in[0];
    const float* h   = (const float*)d_in[1];
    const float* W   = (const float*)d_in[2];
    const float* b   = (const float*)d_in[3];
    const float* a1  = (const float*)d_in[4];
    const float* a2  = (const float*)d_in[5];
    const float* ab  = (const float*)d_in[6];
    float* out = (float*)d_out;

    auto need = [](int c) -> size_t {
        size_t fl = 2 * NN + (size_t)c * NN + (size_t)c * NN * FOUT;
        size_t us = (size_t)FOUT * FIN + (size_t)NN * FOUT;   // Wt + whT bf16
        return fl * 4 + us * 2;
    };
    int C = 4;
    while (C > 1 && need(C) > ws_size) C >>= 1;

    float* fs   = (float*)d_ws;
    float* fd   = fs + NN;
    float* psum = fd + NN;
    float* part = psum + (size_t)C * NN;
    u16*   Wt   = (u16*)(part + (size_t)C * NN * FOUT);
    u16*   whT  = Wt + (size_t)FOUT * FIN;

    k_wt  <<<dim3(FOUT / 64, FIN / 64), 256, 0, stream>>>(W, Wt, fs, fd);
    k_proj<<<dim3(FOUT / 64, NN / 32), 256, 0, stream>>>(h, Wt, b, a1, a2, whT, fs, fd);
    k_attn<<<dim3(NN / BI, C), 256, 0, stream>>>(adj, whT, fs, fd, ab, part, psum);
    k_fin <<<(NN * FOUT / 4) / 256, 256, 0, stream>>>(part, psum, out, C);
}

// Round 2
// 147.598 us; speedup vs baseline: 1.0244x; 1.0142x over previous
//
#include <hip/hip_runtime.h>

#define NN   4096
#define FIN  512
#define FOUT 256
#define ALPHA 0.2f

typedef __attribute__((ext_vector_type(8))) short short8;
typedef __attribute__((ext_vector_type(4))) float f32x4;
typedef unsigned short u16;

__device__ __forceinline__ u16 f2bf(float x) {   // round-to-nearest-even
    union { float f; unsigned u; } v; v.f = x;
    unsigned r = v.u + 0x7FFF + ((v.u >> 16) & 1);
    return (u16)(r >> 16);
}

// ---------------- Kernel 0: Wt[f][k] bf16 = transpose(W [k][f] fp32) ----------------
// Also zeroes fs/fd for k_proj's atomic accumulation (32 blk x 256 thr = 8192 = 2*NN).
__global__ __launch_bounds__(256) void k_wt(const float* __restrict__ W,
                                            u16* __restrict__ Wt,
                                            float* __restrict__ fs,
                                            float* __restrict__ fd) {
    __shared__ float s[64 * 65];
    const int t  = threadIdx.x;
    const int g  = (blockIdx.y * gridDim.x + blockIdx.x) * 256 + t;
    if (g < NN) fs[g] = 0.f; else fd[g - NN] = 0.f;
    const int f0 = blockIdx.x * 64;
    const int k0 = blockIdx.y * 64;
    #pragma unroll
    for (int p = 0; p < 4; ++p) {
        int q = t + 256 * p, rr = q >> 4, cc = q & 15;
        float4 w4 = *(const float4*)&W[(size_t)(k0 + rr) * FOUT + f0 + cc * 4];
        s[(cc * 4 + 0) * 65 + rr] = w4.x;
        s[(cc * 4 + 1) * 65 + rr] = w4.y;
        s[(cc * 4 + 2) * 65 + rr] = w4.z;
        s[(cc * 4 + 3) * 65 + rr] = w4.w;
    }
    __syncthreads();
    #pragma unroll
    for (int p = 0; p < 4; ++p) {
        int q = t + 256 * p, f = q >> 4, kg = q & 15;
        ushort4 o;
        o.x = f2bf(s[f * 65 + kg * 4 + 0]);
        o.y = f2bf(s[f * 65 + kg * 4 + 1]);
        o.z = f2bf(s[f * 65 + kg * 4 + 2]);
        o.w = f2bf(s[f * 65 + kg * 4 + 3]);
        *(ushort4*)&Wt[(size_t)(f0 + f) * FIN + k0 + kg * 4] = o;
    }
}

// ------- Kernel 1: proj -> whT bf16 tiles + f_src/f_dst partials (wh fp32 eliminated) -------
#define HS 520   // u16 LDS row stride (1040 B = 65*16, aligned)
__global__ __launch_bounds__(256) void k_proj(const float* __restrict__ h,
                                              const u16* __restrict__ Wt,
                                              const float* __restrict__ bias,
                                              const float* __restrict__ a1,
                                              const float* __restrict__ a2,
                                              u16* __restrict__ whT,
                                              float* __restrict__ fs,
                                              float* __restrict__ fd) {
    __shared__ u16 s_h[32 * HS];   // 32 rows x 512 k bf16
    const int t  = threadIdx.x;
    const int f0 = blockIdx.x * 64;
    const int i0 = blockIdx.y * 32;
    #pragma unroll
    for (int p = 0; p < 16; ++p) {
        int q = t + 256 * p, row = q >> 7, c4 = q & 127;
        float4 v = *(const float4*)&h[(size_t)(i0 + row) * FIN + c4 * 4];
        ushort4 o; o.x = f2bf(v.x); o.y = f2bf(v.y); o.z = f2bf(v.z); o.w = f2bf(v.w);
        *(ushort4*)&s_h[row * HS + c4 * 4] = o;
    }
    __syncthreads();
    const int w = t >> 6, l = t & 63, n = l & 15, quad = l >> 4;
    const int hh = w & 1, fh = w >> 1;
    f32x4 acc[2] = {{0.f,0.f,0.f,0.f},{0.f,0.f,0.f,0.f}};
    #pragma unroll
    for (int k0 = 0; k0 < FIN; k0 += 32) {
        short8 a = *(const short8*)&s_h[(hh * 16 + n) * HS + k0 + quad * 8];
        short8 b0 = *(const short8*)&Wt[(size_t)(f0 + fh * 32 + n) * FIN + k0 + quad * 8];
        short8 b1 = *(const short8*)&Wt[(size_t)(f0 + fh * 32 + 16 + n) * FIN + k0 + quad * 8];
        acc[0] = __builtin_amdgcn_mfma_f32_16x16x32_bf16(a, b0, acc[0], 0, 0, 0);
        acc[1] = __builtin_amdgcn_mfma_f32_16x16x32_bf16(a, b1, acc[1], 0, 0, 0);
    }
    const int fb = f0 + fh * 32 + n;
    const float bv0 = bias[fb],  bv1 = bias[fb + 16];
    const float a10 = a1[fb],    a11 = a1[fb + 16];
    const float a20 = a2[fb],    a21 = a2[fb + 16];
    u16* wt_tile = whT + (size_t)(i0 >> 5) * (FOUT * 32);
    float d1[4], d2[4];
    #pragma unroll
    for (int r = 0; r < 4; ++r) {
        const int ic = hh * 16 + quad * 4 + r;       // i - i0
        const float v0 = acc[0][r] + bv0;
        const float v1 = acc[1][r] + bv1;
        wt_tile[fb * 32 + ic]        = f2bf(v0);
        wt_tile[(fb + 16) * 32 + ic] = f2bf(v1);
        d1[r] = v0 * a10 + v1 * a11;
        d2[r] = v0 * a20 + v1 * a21;
    }
    #pragma unroll
    for (int m = 1; m < 16; m <<= 1) {
        #pragma unroll
        for (int r = 0; r < 4; ++r) {
            d1[r] += __shfl_xor(d1[r], m);
            d2[r] += __shfl_xor(d2[r], m);
        }
    }
    if (n == 0) {
        #pragma unroll
        for (int r = 0; r < 4; ++r) {
            const int i = i0 + hh * 16 + quad * 4 + r;
            atomicAdd(&fs[i], d1[r]);
            atomicAdd(&fd[i], d2[r]);
        }
    }
}

// ------ Kernel 2: fused mask+exp + MFMA P@wh; raw barrier keeps vmcnt in flight ------
// BI=32 i-rows/block, TJ=64 j/iter, C j-chunks. XOR-swizzled dbuf P tile (row 128B).
// Key fix vs prev round: __syncthreads() drains vmcnt(0) (compiler semantics), which
// serialized the adj prefetch onto the critical path. Raw s_barrier + lgkmcnt(0)-only
// wait lets the HBM prefetch stay in flight across the barrier (T3/T4 minimum form).
#define BI 32
#define TJ 64
__global__ __launch_bounds__(256) void k_attn(const int* __restrict__ adj,
                                              const u16* __restrict__ whT,
                                              const float* __restrict__ fs,
                                              const float* __restrict__ fd,
                                              const float* __restrict__ ab,
                                              float* __restrict__ part,
                                              float* __restrict__ psum) {
    __shared__ u16 s_p[2][BI * 64];    // 2 x 4 KiB, row stride 128 B, swizzled
    const int t  = threadIdx.x;
    const int i0 = blockIdx.x * BI;
    const int c  = blockIdx.y;
    const int jchunk = NN / gridDim.y;
    const int jbeg = c * jchunk, jend = jbeg + jchunk;
    const int jq = t & 15, rh = t >> 4;
    const float fs0 = fs[i0 + rh] + ab[0];
    const float fs1 = fs[i0 + rh + 16] + ab[0];
    const int w = t >> 6, l = t & 63, n = l & 15, quad = l >> 4;

    f32x4 acc[2][4] = {{{0.f,0.f,0.f,0.f},{0.f,0.f,0.f,0.f},{0.f,0.f,0.f,0.f},{0.f,0.f,0.f,0.f}},
                       {{0.f,0.f,0.f,0.f},{0.f,0.f,0.f,0.f},{0.f,0.f,0.f,0.f},{0.f,0.f,0.f,0.f}}};
    float rs0 = 0.f, rs1 = 0.f;

    const size_t arow0 = (size_t)(i0 + rh) * NN;
    const size_t arow1 = (size_t)(i0 + rh + 16) * NN;

    // depth-2 prefetch of adj/fd (covers ~900cy HBM latency at 2 blocks/CU)
    int4   c0 = *(const int4*)&adj[arow0 + jbeg + jq * 4];
    int4   c1 = *(const int4*)&adj[arow1 + jbeg + jq * 4];
    float4 cf = *(const float4*)&fd[jbeg + jq * 4];
    int4   n0 = *(const int4*)&adj[arow0 + jbeg + TJ + jq * 4];
    int4   n1 = *(const int4*)&adj[arow1 + jbeg + TJ + jq * 4];
    float4 nf = *(const float4*)&fd[jbeg + TJ + jq * 4];

    const int wbase = rh * 128 + ((jq * 8) ^ ((rh & 7) << 4));   // write swizzle
    const int rsw   = (n & 7) << 4;                              // read swizzle mask
    int pb = 0;
    for (int j0 = jbeg; j0 < jend; j0 += TJ) {
        // ---- B-frags issued first: L2 latency hides under p-compute ----
        short8 b[2][4];   // [s][u]
        #pragma unroll
        for (int s = 0; s < 2; ++s) {
            const u16* tb = whT + (size_t)((j0 >> 5) + s) * (FOUT * 32) + quad * 8;
            #pragma unroll
            for (int u = 0; u < 4; ++u)
                b[s][u] = *(const short8*)&tb[(w * 64 + u * 16 + n) * 32];
        }
        // ---- compute p from prefetched regs ----
        ushort4 o0, o1;
        {
            float x, p;
            x = fs0 + cf.x; x = x > 0.f ? x : ALPHA * x; p = c0.x > 0 ? __expf(x) : 0.f; o0.x = f2bf(p); rs0 += p;
            x = fs0 + cf.y; x = x > 0.f ? x : ALPHA * x; p = c0.y > 0 ? __expf(x) : 0.f; o0.y = f2bf(p); rs0 += p;
            x = fs0 + cf.z; x = x > 0.f ? x : ALPHA * x; p = c0.z > 0 ? __expf(x) : 0.f; o0.z = f2bf(p); rs0 += p;
            x = fs0 + cf.w; x = x > 0.f ? x : ALPHA * x; p = c0.w > 0 ? __expf(x) : 0.f; o0.w = f2bf(p); rs0 += p;
            x = fs1 + cf.x; x = x > 0.f ? x : ALPHA * x; p = c1.x > 0 ? __expf(x) : 0.f; o1.x = f2bf(p); rs1 += p;
            x = fs1 + cf.y; x = x > 0.f ? x : ALPHA * x; p = c1.y > 0 ? __expf(x) : 0.f; o1.y = f2bf(p); rs1 += p;
            x = fs1 + cf.z; x = x > 0.f ? x : ALPHA * x; p = c1.z > 0 ? __expf(x) : 0.f; o1.z = f2bf(p); rs1 += p;
            x = fs1 + cf.w; x = x > 0.f ? x : ALPHA * x; p = c1.w > 0 ? __expf(x) : 0.f; o1.w = f2bf(p); rs1 += p;
        }
        // ---- write this iter's P tile into buffer pb ----
        char* spB = (char*)s_p + pb * 4096;
        *(ushort4*)(spB + wbase)        = o0;   // row rh
        *(ushort4*)(spB + 2048 + wbase) = o1;   // row rh+16 (same xor: (rh+16)&7 == rh&7)
        // ---- shift prefetch regs; issue depth-2 prefetch (stays in flight across barrier) ----
        c0 = n0; c1 = n1; cf = nf;
        if (j0 + 2 * TJ < jend) {
            n0 = *(const int4*)&adj[arow0 + j0 + 2 * TJ + jq * 4];
            n1 = *(const int4*)&adj[arow1 + j0 + 2 * TJ + jq * 4];
            nf = *(const float4*)&fd[j0 + 2 * TJ + jq * 4];
        }
        // ---- barrier: drain LDS writes only; vmcnt (adj prefetch) stays outstanding ----
        asm volatile("s_waitcnt lgkmcnt(0)" ::: "memory");
        __builtin_amdgcn_s_barrier();
        __builtin_amdgcn_sched_barrier(0);
        // ---- MFMA: 32i x 64f slice per wave ----
        __builtin_amdgcn_s_setprio(1);
        #pragma unroll
        for (int s = 0; s < 2; ++s) {
            const int rb = n * 128 + ((s * 64 + quad * 16) ^ rsw);
            short8 a0  = *(const short8*)(spB + rb);          // row n
            short8 a1f = *(const short8*)(spB + 2048 + rb);   // row 16+n
            #pragma unroll
            for (int u = 0; u < 4; ++u) {
                acc[0][u] = __builtin_amdgcn_mfma_f32_16x16x32_bf16(a0,  b[s][u], acc[0][u], 0, 0, 0);
                acc[1][u] = __builtin_amdgcn_mfma_f32_16x16x32_bf16(a1f, b[s][u], acc[1][u], 0, 0, 0);
            }
        }
        __builtin_amdgcn_s_setprio(0);
        pb ^= 1;
    }
    // ---- partial denominators: reduce over the 16 jq lanes ----
    #pragma unroll
    for (int m = 8; m > 0; m >>= 1) {
        rs0 += __shfl_xor(rs0, m);
        rs1 += __shfl_xor(rs1, m);
    }
    if (jq == 0) {
        psum[(size_t)c * NN + i0 + rh]      = rs0;
        psum[(size_t)c * NN + i0 + rh + 16] = rs1;
    }
    // ---- partial numerators ----
    float* pc = part + ((size_t)c * NN + i0) * FOUT;
    #pragma unroll
    for (int hf = 0; hf < 2; ++hf)
        #pragma unroll
        for (int u = 0; u < 4; ++u)
            #pragma unroll
            for (int r = 0; r < 4; ++r)
                pc[(size_t)(hf * 16 + quad * 4 + r) * FOUT + w * 64 + u * 16 + n] = acc[hf][u][r];
}

// ------ Kernel 3: combine partials, normalize, elu ------
__global__ __launch_bounds__(256) void k_fin(const float* __restrict__ part,
                                             const float* __restrict__ psum,
                                             float* __restrict__ out, int C) {
    const int g = blockIdx.x * 256 + threadIdx.x;
    const int i = g >> 6;
    const size_t s4 = (size_t)NN * FOUT / 4;
    float4 a = ((const float4*)part)[g];
    float s = psum[i];
    for (int c = 1; c < C; ++c) {
        float4 bb = ((const float4*)part)[g + (size_t)c * s4];
        a.x += bb.x; a.y += bb.y; a.z += bb.z; a.w += bb.w;
        s += psum[(size_t)c * NN + i];
    }
    const float inv = 1.0f / s;
    a.x *= inv; a.y *= inv; a.z *= inv; a.w *= inv;
    a.x = a.x > 0.f ? a.x : __expf(a.x) - 1.f;
    a.y = a.y > 0.f ? a.y : __expf(a.y) - 1.f;
    a.z = a.z > 0.f ? a.z : __expf(a.z) - 1.f;
    a.w = a.w > 0.f ? a.w : __expf(a.w) - 1.f;
    ((float4*)out)[g] = a;
}

extern "C" void kernel_launch(void* const* d_in, const int* in_sizes, int n_in,
                              void* d_out, int out_size, void* d_ws, size_t ws_size,
                              hipStream_t stream) {
    const int*   adj = (const int*)  d_in[0];
    const float* h   = (const float*)d_in[1];
    const float* W   = (const float*)d_in[2];
    const float* b   = (const float*)d_in[3];
    const float* a1  = (const float*)d_in[4];
    const float* a2  = (const float*)d_in[5];
    const float* ab  = (const float*)d_in[6];
    float* out = (float*)d_out;

    auto need = [](int c) -> size_t {
        size_t fl = 2 * NN + (size_t)c * NN + (size_t)c * NN * FOUT;
        size_t us = (size_t)FOUT * FIN + (size_t)NN * FOUT;   // Wt + whT bf16
        return fl * 4 + us * 2;
    };
    int C = 4;
    while (C > 1 && need(C) > ws_size) C >>= 1;

    float* fs   = (float*)d_ws;
    float* fd   = fs + NN;
    float* psum = fd + NN;
    float* part = psum + (size_t)C * NN;
    u16*   Wt   = (u16*)(part + (size_t)C * NN * FOUT);
    u16*   whT  = Wt + (size_t)FOUT * FIN;

    k_wt  <<<dim3(FOUT / 64, FIN / 64), 256, 0, stream>>>(W, Wt, fs, fd);
    k_proj<<<dim3(FOUT / 64, NN / 32), 256, 0, stream>>>(h, Wt, b, a1, a2, whT, fs, fd);
    k_attn<<<dim3(NN / BI, C), 256, 0, stream>>>(adj, whT, fs, fd, ab, part, psum);
    k_fin <<<(NN * FOUT / 4) / 256, 256, 0, stream>>>(part, psum, out, C);
}